// Round 7
// baseline (189.199 us; speedup 1.0000x reference)
//
#include <hip/hip_runtime.h>
#include <hip/hip_bf16.h>
#include <math.h>

#define BATCH 8
#define L_SEQ 8192
#define KD    256   // contraction dim for both GEMMs (c / n)

typedef __attribute__((ext_vector_type(8))) short bf16x8;
typedef __attribute__((ext_vector_type(4))) float f32x4;

__device__ __forceinline__ void async_ld16(const __hip_bfloat16* g, __hip_bfloat16* l) {
    __builtin_amdgcn_global_load_lds(
        (const __attribute__((address_space(1))) unsigned int*)g,
        (__attribute__((address_space(3))) unsigned int*)l, 16, 0, 0);
}

// ---------------------------------------------------------------------------
// prep: W1bf[n][c] = bf16(B[n][c]*dt[n]); Cbf[d][n] = bf16(C[d][n]);
// lamtab[n*4+0] = lambda, +1 = lambda^16, +2 = lambda^128, +3 = (dAr, dAi)
// ---------------------------------------------------------------------------
__global__ void prep(const float* __restrict__ B, const float* __restrict__ logdt,
                     const float* __restrict__ C, const float* __restrict__ A,
                     __hip_bfloat16* __restrict__ W1bf, __hip_bfloat16* __restrict__ Cbf,
                     float2* __restrict__ lamtab) {
    int i = blockIdx.x * 256 + threadIdx.x;
    W1bf[i] = __float2bfloat16(B[i] * expf(logdt[i >> 8]));
    Cbf[i]  = __float2bfloat16(C[i]);
    if (blockIdx.x == 0) {
        int n = threadIdx.x;
        float dt  = expf(logdt[n]);
        float dAr = -dt * log1pf(expf(A[2 * n]));
        float dAi = dt * A[2 * n + 1];
        float e1 = expf(dAr);
        lamtab[n * 4 + 0] = make_float2(e1 * cosf(dAi), e1 * sinf(dAi));
        float e16 = expf(16.f * dAr);
        lamtab[n * 4 + 1] = make_float2(e16 * cosf(16.f * dAi), e16 * sinf(16.f * dAi));
        float e128 = expf(128.f * dAr);
        lamtab[n * 4 + 2] = make_float2(e128 * cosf(128.f * dAi), e128 * sinf(128.f * dAi));
        lamtab[n * 4 + 3] = make_float2(dAr, dAi);
    }
}

// ---------------------------------------------------------------------------
// GEMM1 — byte-identical to the verified round-0 baseline (NO-TOUCH ZONE:
// three structurally different edits all failed the tolerance via perturbed
// seg-summary codegen; this exact compilation is proven).
// ---------------------------------------------------------------------------
__global__ __launch_bounds__(256) void gemm1(
        const float* __restrict__ X, const __hip_bfloat16* __restrict__ W1,
        const float2* __restrict__ lamtab,
        __hip_bfloat16* __restrict__ XBT, float2* __restrict__ sums)
{
    __shared__ __hip_bfloat16 Abuf[16 * 512];
    __shared__ __hip_bfloat16 Bbuf[16 * 512];

    const int t = threadIdx.x, lane = t & 63, wave = t >> 6;
    const int wr = wave >> 1, wc = wave & 1;
    const int lm = lane & 15, lq = lane >> 4;
    const int seg = blockIdx.y;
    const int row0 = seg * 128;            // l
    const int col0 = blockIdx.x * 128;     // n
    const int b = blockIdx.z;
    const float* Xb = X + (size_t)b * KD * L_SEQ;

    // A-staging role: thread owns c-block of 8 (one LDS slot) x 4 l's
    const int c8  = t >> 5;        // 0..7
    const int l4  = (t & 31) * 4;  // 0..124
    const int s_w = c8 >> 2;       // k-half
    const int lq_w = c8 & 3;

    f32x4 acc[4][4];
#pragma unroll
    for (int i = 0; i < 4; ++i)
#pragma unroll
        for (int j = 0; j < 4; ++j) acc[i][j] = {0.f, 0.f, 0.f, 0.f};

    for (int k0 = 0; k0 < KD; k0 += 64) {
        // B tile (W1, k-contig) via async 16B direct-to-LDS
#pragma unroll
        for (int i = 0; i < 4; ++i) {
            int jb = wave * 4 + i, ct = jb >> 1, sB = jb & 1;
            const __hip_bfloat16* g =
                W1 + (size_t)(col0 + ct * 16 + lm) * KD + k0 + sB * 32 + lq * 8;
            async_ld16(g, &Bbuf[jb * 512 + lane * 8]);
        }
        // A tile: load x fp32 [c][l], transpose+cast into swizzled frag order
        float4 xv[8];
#pragma unroll
        for (int i = 0; i < 8; ++i)
            xv[i] = *(const float4*)(Xb + (size_t)(k0 + c8 * 8 + i) * L_SEQ + row0 + l4);
#pragma unroll
        for (int j = 0; j < 4; ++j) {
            int l = l4 + j;
            int rt = l >> 4, lmW = l & 15;
            union { __hip_bfloat16 h[8]; uint4 u; } pk;
#pragma unroll
            for (int i = 0; i < 8; ++i) {
                const float* f = (const float*)&xv[i];
                pk.h[i] = __float2bfloat16(f[j]);
            }
            int slot = (lmW ^ rt ^ (s_w << 3)) + 16 * lq_w;
            *(uint4*)&Abuf[(rt * 2 + s_w) * 512 + slot * 8] = pk.u;
        }
        __syncthreads();
#pragma unroll
        for (int s = 0; s < 2; ++s) {
            bf16x8 af[4], bfr[4];
#pragma unroll
            for (int i = 0; i < 4; ++i) {
                int rt = wr * 4 + i;
                int slot = (lm ^ rt ^ (s << 3)) + 16 * lq;
                af[i] = *(const bf16x8*)&Abuf[(rt * 2 + s) * 512 + slot * 8];
            }
#pragma unroll
            for (int j = 0; j < 4; ++j)
                bfr[j] = *(const bf16x8*)&Bbuf[((wc * 4 + j) * 2 + s) * 512 + lane * 8];
#pragma unroll
            for (int i = 0; i < 4; ++i)
#pragma unroll
                for (int j = 0; j < 4; ++j)
                    acc[i][j] = __builtin_amdgcn_mfma_f32_16x16x32_bf16(
                        af[i], bfr[j], acc[i][j], 0, 0, 0);
        }
        __syncthreads();
    }

    // ---- write xb_t (bf16)
    __hip_bfloat16* Db = XBT + (size_t)b * L_SEQ * KD;
#pragma unroll
    for (int i = 0; i < 4; ++i) {
        int r0 = row0 + wr * 64 + i * 16 + lq * 4;
#pragma unroll
        for (int j = 0; j < 4; ++j) {
            int c = col0 + wc * 64 + j * 16 + lm;
#pragma unroll
            for (int r = 0; r < 4; ++r)
                Db[(size_t)(r0 + r) * KD + c] = __float2bfloat16(acc[i][j][r]);
        }
    }

    // ---- seg summaries: sum_l lambda^(127-l) * acc
    float2 par[4];
#pragma unroll
    for (int j = 0; j < 4; ++j) {
        int n = col0 + wc * 64 + j * 16 + lm;
        float2 dA  = lamtab[n * 4 + 3];
        float2 lam = lamtab[n * 4 + 0];
        float m1r = lam.x, m1i = lam.y;      // lambda (FIXED: was lambda^-1)
        float sr = 0.f, si = 0.f;
#pragma unroll
        for (int i = 0; i < 4; ++i) {
            int lbase = wr * 64 + i * 16 + lq * 4;
            float p = (float)(127 - lbase - 3);
            float er = expf(dA.x * p);
            float wrr = er * cosf(dA.y * p), wii = er * sinf(dA.y * p);
            for (int r = 3; r >= 0; --r) {
                float v = acc[i][j][r];
                sr += wrr * v; si += wii * v;
                float nr = wrr * m1r - wii * m1i;
                float ni = wrr * m1i + wii * m1r;
                wrr = nr; wii = ni;
            }
        }
        sr += __shfl_xor(sr, 16); si += __shfl_xor(si, 16);
        sr += __shfl_xor(sr, 32); si += __shfl_xor(si, 32);
        par[j] = make_float2(sr, si);
    }
    float2* ssum = (float2*)Bbuf;   // reuse LDS (all waves past final sync)
    if (wr == 0 && lq == 0) {
#pragma unroll
        for (int j = 0; j < 4; ++j) ssum[wc * 64 + j * 16 + lm] = par[j];
    }
    __syncthreads();
    if (wr == 1 && lq == 0) {
#pragma unroll
        for (int j = 0; j < 4; ++j) {
            float2 o = ssum[wc * 64 + j * 16 + lm];
            int n = col0 + wc * 64 + j * 16 + lm;
            sums[((size_t)b * KD + n) * 64 + seg] =
                make_float2(par[j].x + o.x, par[j].y + o.y);
        }
    }
}

// ---------------------------------------------------------------------------
// scan_carry: per (b,n) wave-scan 64 inclusive seg summaries -> exclusive carries
// ---------------------------------------------------------------------------
__global__ __launch_bounds__(64) void scan_carry(
        const float2* __restrict__ lamtab, float2* __restrict__ sums) {
    const int lane = threadIdx.x;
    const int b = blockIdx.x >> 8, n = blockIdx.x & 255;
    float2 m = lamtab[n * 4 + 2];   // lambda^128
    float mr = m.x, mi = m.y;
    float2 s = sums[((size_t)b * KD + n) * 64 + lane];
    float vr = s.x, vi = s.y;
#pragma unroll
    for (int d = 1; d < 64; d <<= 1) {
        float ur = __shfl_up(vr, (unsigned)d);
        float ui = __shfl_up(vi, (unsigned)d);
        if (lane >= d) {
            float tr = mr * ur - mi * ui + vr;
            float ti = mr * ui + mi * ur + vi;
            vr = tr; vi = ti;
        }
        float m2r = mr * mr - mi * mi;
        float m2i = 2.0f * mr * mi;
        mr = m2r; mi = m2i;
    }
    float cr = __shfl_up(vr, 1u), ci = __shfl_up(vi, 1u);
    if (lane == 0) { cr = 0.f; ci = 0.f; }
    sums[((size_t)b * KD + n) * 64 + lane] = make_float2(cr, ci);
}

// ---------------------------------------------------------------------------
// FUSED scan+GEMM2 — replaces scan_apply + gemm2.
// Block = (seg, dtile, b). Phase A: scan_apply's exact 3-phase code (same
// 256-thread mapping, same per-n recurrence order) but y goes to LDS in MFMA
// fragment layout instead of global. Phase B: r0-gemm2's MFMA loop (same
// kt/s accumulation order), A-operand (Cbf, k-contiguous, L2-resident) via
// direct global->reg fragments (values-proven in r4).
// LDS: Ybuf[4][16*512] bf16 = 64KB; sl[8][258] float2 aliases its head
// (sl is dead before Ybuf's first write — see barrier placement).
// Fragment slot XOR-swizzle (lm ^ lq ^ (s<<2)) on BOTH write and read:
// writes 16-way -> 2-way (free); reads stay per-quarter-wave permutations.
// ---------------------------------------------------------------------------
__global__ __launch_bounds__(256) void scan_gemm2(
        const __hip_bfloat16* __restrict__ XBT,   // xb_t [B][L][256] (pre-scan)
        const float2* __restrict__ lamtab,
        const float2* __restrict__ sums,
        const __hip_bfloat16* __restrict__ Ag,    // Cbf [256][256]
        float* __restrict__ Dg)                   // out [B][256][L]
{
    __shared__ __align__(16) char lds_raw[65536];
    __hip_bfloat16 (*Ybuf)[16 * 512] = (__hip_bfloat16 (*)[16 * 512])lds_raw;
    float2 (*sl)[258] = (float2 (*)[258])lds_raw;   // aliases Ybuf head

    const int t = threadIdx.x;
    const int seg = blockIdx.x, dtile = blockIdx.y, b = blockIdx.z;
    const int sub = t >> 5, n0 = (t & 31) * 8;

    // ================= scan (verbatim scan_apply math) =================
    const __hip_bfloat16* base =
        XBT + ((size_t)b * L_SEQ + seg * 128 + sub * 16) * KD + n0;

    float2 lam[8];
#pragma unroll
    for (int k = 0; k < 8; ++k) lam[k] = lamtab[(n0 + k) * 4];

    uint4 xv[16];
    float sr[8], si[8];
#pragma unroll
    for (int k = 0; k < 8; ++k) { sr[k] = 0.f; si[k] = 0.f; }

    // phase 1: local scan of 16 l's (x cached in regs)
#pragma unroll
    for (int l = 0; l < 16; ++l) {
        xv[l] = *(const uint4*)(base + (size_t)l * KD);
        const __hip_bfloat16* xs = (const __hip_bfloat16*)&xv[l];
#pragma unroll
        for (int k = 0; k < 8; ++k) {
            float v = __bfloat162float(xs[k]);
            float nr = lam[k].x * sr[k] - lam[k].y * si[k] + v;
            float ni = lam[k].x * si[k] + lam[k].y * sr[k];
            sr[k] = nr; si[k] = ni;
        }
    }
#pragma unroll
    for (int k = 0; k < 8; ++k) sl[sub][n0 + k] = make_float2(sr[k], si[k]);
    __syncthreads();

    // phase 2: per-n scan across the 8 sub-chunks (thread t owns n=t)
    {
        int n = t;
        float2 m16 = lamtab[n * 4 + 1];
        float2 c = sums[((size_t)b * KD + n) * 64 + seg];
        float cr = c.x, ci = c.y;
#pragma unroll
        for (int s2 = 0; s2 < 8; ++s2) {
            float2 loc = sl[s2][n];
            sl[s2][n] = make_float2(cr, ci);     // exclusive carry for sub-chunk
            float nr = m16.x * cr - m16.y * ci + loc.x;
            float ni = m16.x * ci + m16.y * cr + loc.y;
            cr = nr; ci = ni;
        }
    }
    __syncthreads();

    // phase 3 head: carries -> regs (sl is DEAD after this + barrier)
#pragma unroll
    for (int k = 0; k < 8; ++k) {
        float2 c = sl[sub][n0 + k];
        sr[k] = c.x; si[k] = c.y;
    }
    __syncthreads();   // all sl reads done; Ybuf writes may now alias

    // phase 3: rescan with carry, y (bf16x8) -> LDS fragment slots
    {
        const int kt_w = n0 >> 6, s_w = (n0 >> 5) & 1, lq_w = (n0 >> 3) & 3;
#pragma unroll
        for (int l = 0; l < 16; ++l) {
            const __hip_bfloat16* xs = (const __hip_bfloat16*)&xv[l];
            union { __hip_bfloat16 h[8]; uint4 u; } yv;
#pragma unroll
            for (int k = 0; k < 8; ++k) {
                float v = __bfloat162float(xs[k]);
                float nr = lam[k].x * sr[k] - lam[k].y * si[k] + v;
                float ni = lam[k].x * si[k] + lam[k].y * sr[k];
                sr[k] = nr; si[k] = ni;
                yv.h[k] = __float2bfloat16(nr);
            }
            int slotS = lq_w * 16 + (l ^ lq_w ^ (s_w << 2));   // XOR-swizzled
            *(uint4*)&Ybuf[kt_w][(sub * 2 + s_w) * 512 + slotS * 8] = yv.u;
        }
    }
    __syncthreads();

    // ================= GEMM2 MFMA (r0 accumulation order) =================
    const int lane = t & 63, wave = t >> 6;
    const int wr = wave >> 1, wc = wave & 1;
    const int lm = lane & 15, lq = lane >> 4;
    const int row0 = dtile * 128, col0 = seg * 128;
    const __hip_bfloat16* Ab = Ag + (size_t)(row0 + wr * 64 + lm) * KD + lq * 8;
    float* Db = Dg + (size_t)b * KD * L_SEQ;

    f32x4 acc[4][4];
#pragma unroll
    for (int i = 0; i < 4; ++i)
#pragma unroll
        for (int j = 0; j < 4; ++j) acc[i][j] = {0.f, 0.f, 0.f, 0.f};

#pragma unroll
    for (int kt = 0; kt < 4; ++kt) {
#pragma unroll
        for (int s = 0; s < 2; ++s) {
            bf16x8 af[4], bfr[4];
#pragma unroll
            for (int i = 0; i < 4; ++i)
                af[i] = *(const bf16x8*)(Ab + (size_t)(i * 16) * KD + kt * 64 + s * 32);
            int slotS = lq * 16 + (lm ^ lq ^ (s << 2));        // matching swizzle
#pragma unroll
            for (int j = 0; j < 4; ++j)
                bfr[j] = *(const bf16x8*)&Ybuf[kt][((wc * 4 + j) * 2 + s) * 512 + slotS * 8];
#pragma unroll
            for (int i = 0; i < 4; ++i)
#pragma unroll
                for (int j = 0; j < 4; ++j)
                    acc[i][j] = __builtin_amdgcn_mfma_f32_16x16x32_bf16(
                        af[i], bfr[j], acc[i][j], 0, 0, 0);
        }
    }

#pragma unroll
    for (int i = 0; i < 4; ++i) {
        int r0 = row0 + wr * 64 + i * 16 + lq * 4;
#pragma unroll
        for (int j = 0; j < 4; ++j) {
            int c = col0 + wc * 64 + j * 16 + lm;
#pragma unroll
            for (int r = 0; r < 4; ++r)
                Db[(size_t)(r0 + r) * L_SEQ + c] = acc[i][j][r];
        }
    }
}

// ---------------------------------------------------------------------------
// Launch
// ---------------------------------------------------------------------------
extern "C" void kernel_launch(void* const* d_in, const int* in_sizes, int n_in,
                              void* d_out, int out_size, void* d_ws, size_t ws_size,
                              hipStream_t stream) {
    const float* x      = (const float*)d_in[0];
    const float* A      = (const float*)d_in[1];
    const float* B      = (const float*)d_in[2];
    const float* log_dt = (const float*)d_in[3];
    const float* C      = (const float*)d_in[4];
    float* out = (float*)d_out;

    char* ws = (char*)d_ws;
    __hip_bfloat16* W1bf = (__hip_bfloat16*)(ws);                  // 128 KB
    __hip_bfloat16* Cbf  = (__hip_bfloat16*)(ws + (128 << 10));    // 128 KB
    float2*         lamtab = (float2*)(ws + (256 << 10));          // 8 KB
    float2*         sums = (float2*)(ws + (320 << 10));            // 1 MB
    __hip_bfloat16* xb_t = (__hip_bfloat16*)(ws + ((size_t)2 << 20)); // 32 MB

    prep<<<256, 256, 0, stream>>>(B, log_dt, C, A, W1bf, Cbf, lamtab);
    gemm1<<<dim3(2, 64, BATCH), 256, 0, stream>>>(x, W1bf, lamtab, xb_t, sums);
    scan_carry<<<BATCH * KD, 64, 0, stream>>>(lamtab, sums);
    scan_gemm2<<<dim3(64, 2, BATCH), 256, 0, stream>>>(xb_t, lamtab, sums, Cbf, out);
}

// Round 8
// 179.840 us; speedup vs baseline: 1.0520x; 1.0520x over previous
//
#include <hip/hip_runtime.h>
#include <hip/hip_bf16.h>
#include <math.h>

#define BATCH 8
#define L_SEQ 8192
#define KD    256   // contraction dim for both GEMMs (c / n)

typedef __attribute__((ext_vector_type(8))) short bf16x8;
typedef __attribute__((ext_vector_type(4))) float f32x4;

__device__ __forceinline__ void async_ld16(const __hip_bfloat16* g, __hip_bfloat16* l) {
    __builtin_amdgcn_global_load_lds(
        (const __attribute__((address_space(1))) unsigned int*)g,
        (__attribute__((address_space(3))) unsigned int*)l, 16, 0, 0);
}

// ---------------------------------------------------------------------------
// prep: W1bf[n][c] = bf16(B[n][c]*dt[n]); Cbf[d][n] = bf16(C[d][n]);
// lamtab[n*4+0] = lambda, +1 = lambda^16, +2 = lambda^128, +3 = (dAr, dAi)
// ---------------------------------------------------------------------------
__global__ void prep(const float* __restrict__ B, const float* __restrict__ logdt,
                     const float* __restrict__ C, const float* __restrict__ A,
                     __hip_bfloat16* __restrict__ W1bf, __hip_bfloat16* __restrict__ Cbf,
                     float2* __restrict__ lamtab) {
    int i = blockIdx.x * 256 + threadIdx.x;
    W1bf[i] = __float2bfloat16(B[i] * expf(logdt[i >> 8]));
    Cbf[i]  = __float2bfloat16(C[i]);
    if (blockIdx.x == 0) {
        int n = threadIdx.x;
        float dt  = expf(logdt[n]);
        float dAr = -dt * log1pf(expf(A[2 * n]));
        float dAi = dt * A[2 * n + 1];
        float e1 = expf(dAr);
        lamtab[n * 4 + 0] = make_float2(e1 * cosf(dAi), e1 * sinf(dAi));
        float e16 = expf(16.f * dAr);
        lamtab[n * 4 + 1] = make_float2(e16 * cosf(16.f * dAi), e16 * sinf(16.f * dAi));
        float e128 = expf(128.f * dAr);
        lamtab[n * 4 + 2] = make_float2(e128 * cosf(128.f * dAi), e128 * sinf(128.f * dAi));
        lamtab[n * 4 + 3] = make_float2(dAr, dAi);
    }
}

// ---------------------------------------------------------------------------
// GEMM1 — byte-identical to the verified round-0 baseline (NO-TOUCH ZONE:
// three structurally different edits all failed the tolerance via perturbed
// seg-summary codegen; this exact compilation is proven).
// ---------------------------------------------------------------------------
__global__ __launch_bounds__(256) void gemm1(
        const float* __restrict__ X, const __hip_bfloat16* __restrict__ W1,
        const float2* __restrict__ lamtab,
        __hip_bfloat16* __restrict__ XBT, float2* __restrict__ sums)
{
    __shared__ __hip_bfloat16 Abuf[16 * 512];
    __shared__ __hip_bfloat16 Bbuf[16 * 512];

    const int t = threadIdx.x, lane = t & 63, wave = t >> 6;
    const int wr = wave >> 1, wc = wave & 1;
    const int lm = lane & 15, lq = lane >> 4;
    const int seg = blockIdx.y;
    const int row0 = seg * 128;            // l
    const int col0 = blockIdx.x * 128;     // n
    const int b = blockIdx.z;
    const float* Xb = X + (size_t)b * KD * L_SEQ;

    // A-staging role: thread owns c-block of 8 (one LDS slot) x 4 l's
    const int c8  = t >> 5;        // 0..7
    const int l4  = (t & 31) * 4;  // 0..124
    const int s_w = c8 >> 2;       // k-half
    const int lq_w = c8 & 3;

    f32x4 acc[4][4];
#pragma unroll
    for (int i = 0; i < 4; ++i)
#pragma unroll
        for (int j = 0; j < 4; ++j) acc[i][j] = {0.f, 0.f, 0.f, 0.f};

    for (int k0 = 0; k0 < KD; k0 += 64) {
        // B tile (W1, k-contig) via async 16B direct-to-LDS
#pragma unroll
        for (int i = 0; i < 4; ++i) {
            int jb = wave * 4 + i, ct = jb >> 1, sB = jb & 1;
            const __hip_bfloat16* g =
                W1 + (size_t)(col0 + ct * 16 + lm) * KD + k0 + sB * 32 + lq * 8;
            async_ld16(g, &Bbuf[jb * 512 + lane * 8]);
        }
        // A tile: load x fp32 [c][l], transpose+cast into swizzled frag order
        float4 xv[8];
#pragma unroll
        for (int i = 0; i < 8; ++i)
            xv[i] = *(const float4*)(Xb + (size_t)(k0 + c8 * 8 + i) * L_SEQ + row0 + l4);
#pragma unroll
        for (int j = 0; j < 4; ++j) {
            int l = l4 + j;
            int rt = l >> 4, lmW = l & 15;
            union { __hip_bfloat16 h[8]; uint4 u; } pk;
#pragma unroll
            for (int i = 0; i < 8; ++i) {
                const float* f = (const float*)&xv[i];
                pk.h[i] = __float2bfloat16(f[j]);
            }
            int slot = (lmW ^ rt ^ (s_w << 3)) + 16 * lq_w;
            *(uint4*)&Abuf[(rt * 2 + s_w) * 512 + slot * 8] = pk.u;
        }
        __syncthreads();
#pragma unroll
        for (int s = 0; s < 2; ++s) {
            bf16x8 af[4], bfr[4];
#pragma unroll
            for (int i = 0; i < 4; ++i) {
                int rt = wr * 4 + i;
                int slot = (lm ^ rt ^ (s << 3)) + 16 * lq;
                af[i] = *(const bf16x8*)&Abuf[(rt * 2 + s) * 512 + slot * 8];
            }
#pragma unroll
            for (int j = 0; j < 4; ++j)
                bfr[j] = *(const bf16x8*)&Bbuf[((wc * 4 + j) * 2 + s) * 512 + lane * 8];
#pragma unroll
            for (int i = 0; i < 4; ++i)
#pragma unroll
                for (int j = 0; j < 4; ++j)
                    acc[i][j] = __builtin_amdgcn_mfma_f32_16x16x32_bf16(
                        af[i], bfr[j], acc[i][j], 0, 0, 0);
        }
        __syncthreads();
    }

    // ---- write xb_t (bf16)
    __hip_bfloat16* Db = XBT + (size_t)b * L_SEQ * KD;
#pragma unroll
    for (int i = 0; i < 4; ++i) {
        int r0 = row0 + wr * 64 + i * 16 + lq * 4;
#pragma unroll
        for (int j = 0; j < 4; ++j) {
            int c = col0 + wc * 64 + j * 16 + lm;
#pragma unroll
            for (int r = 0; r < 4; ++r)
                Db[(size_t)(r0 + r) * KD + c] = __float2bfloat16(acc[i][j][r]);
        }
    }

    // ---- seg summaries: sum_l lambda^(127-l) * acc
    float2 par[4];
#pragma unroll
    for (int j = 0; j < 4; ++j) {
        int n = col0 + wc * 64 + j * 16 + lm;
        float2 dA  = lamtab[n * 4 + 3];
        float2 lam = lamtab[n * 4 + 0];
        float m1r = lam.x, m1i = lam.y;      // lambda (FIXED: was lambda^-1)
        float sr = 0.f, si = 0.f;
#pragma unroll
        for (int i = 0; i < 4; ++i) {
            int lbase = wr * 64 + i * 16 + lq * 4;
            float p = (float)(127 - lbase - 3);
            float er = expf(dA.x * p);
            float wrr = er * cosf(dA.y * p), wii = er * sinf(dA.y * p);
            for (int r = 3; r >= 0; --r) {
                float v = acc[i][j][r];
                sr += wrr * v; si += wii * v;
                float nr = wrr * m1r - wii * m1i;
                float ni = wrr * m1i + wii * m1r;
                wrr = nr; wii = ni;
            }
        }
        sr += __shfl_xor(sr, 16); si += __shfl_xor(si, 16);
        sr += __shfl_xor(sr, 32); si += __shfl_xor(si, 32);
        par[j] = make_float2(sr, si);
    }
    float2* ssum = (float2*)Bbuf;   // reuse LDS (all waves past final sync)
    if (wr == 0 && lq == 0) {
#pragma unroll
        for (int j = 0; j < 4; ++j) ssum[wc * 64 + j * 16 + lm] = par[j];
    }
    __syncthreads();
    if (wr == 1 && lq == 0) {
#pragma unroll
        for (int j = 0; j < 4; ++j) {
            float2 o = ssum[wc * 64 + j * 16 + lm];
            int n = col0 + wc * 64 + j * 16 + lm;
            sums[((size_t)b * KD + n) * 64 + seg] =
                make_float2(par[j].x + o.x, par[j].y + o.y);
        }
    }
}

// ---------------------------------------------------------------------------
// scan_carry: per (b,n) wave-scan 64 inclusive seg summaries -> exclusive carries
// ---------------------------------------------------------------------------
__global__ __launch_bounds__(64) void scan_carry(
        const float2* __restrict__ lamtab, float2* __restrict__ sums) {
    const int lane = threadIdx.x;
    const int b = blockIdx.x >> 8, n = blockIdx.x & 255;
    float2 m = lamtab[n * 4 + 2];   // lambda^128
    float mr = m.x, mi = m.y;
    float2 s = sums[((size_t)b * KD + n) * 64 + lane];
    float vr = s.x, vi = s.y;
#pragma unroll
    for (int d = 1; d < 64; d <<= 1) {
        float ur = __shfl_up(vr, (unsigned)d);
        float ui = __shfl_up(vi, (unsigned)d);
        if (lane >= d) {
            float tr = mr * ur - mi * ui + vr;
            float ti = mr * ui + mi * ur + vi;
            vr = tr; vi = ti;
        }
        float m2r = mr * mr - mi * mi;
        float m2i = 2.0f * mr * mi;
        mr = m2r; mi = m2i;
    }
    float cr = __shfl_up(vr, 1u), ci = __shfl_up(vi, 1u);
    if (lane == 0) { cr = 0.f; ci = 0.f; }
    sums[((size_t)b * KD + n) * 64 + lane] = make_float2(cr, ci);
}

// ---------------------------------------------------------------------------
// FUSED scan+GEMM2 v2 — one block per (seg,b); dtile LOOPED INSIDE.
// vs r7 (PASSED): scan runs ONCE per segment (was 2x, once per dtile), and
// grid halves to 512 blocks = 2/CU = ONE generation (was 2). Per-dtile
// arithmetic is instruction-identical to an r7 block: same scan math, same
// carries, same MFMA order, acc re-zeroed per dtile -> same out values.
// ---------------------------------------------------------------------------
__global__ __launch_bounds__(256) void scan_gemm2(
        const __hip_bfloat16* __restrict__ XBT,   // xb_t [B][L][256] (pre-scan)
        const float2* __restrict__ lamtab,
        const float2* __restrict__ sums,
        const __hip_bfloat16* __restrict__ Ag,    // Cbf [256][256]
        float* __restrict__ Dg)                   // out [B][256][L]
{
    __shared__ __align__(16) char lds_raw[65536];
    __hip_bfloat16 (*Ybuf)[16 * 512] = (__hip_bfloat16 (*)[16 * 512])lds_raw;
    float2 (*sl)[258] = (float2 (*)[258])lds_raw;   // aliases Ybuf head

    const int t = threadIdx.x;
    const int seg = blockIdx.x, b = blockIdx.y;
    const int sub = t >> 5, n0 = (t & 31) * 8;

    // ================= scan (verbatim r7 math, run ONCE) =================
    const __hip_bfloat16* base =
        XBT + ((size_t)b * L_SEQ + seg * 128 + sub * 16) * KD + n0;

    float2 lam[8];
#pragma unroll
    for (int k = 0; k < 8; ++k) lam[k] = lamtab[(n0 + k) * 4];

    uint4 xv[16];
    float sr[8], si[8];
#pragma unroll
    for (int k = 0; k < 8; ++k) { sr[k] = 0.f; si[k] = 0.f; }

    // phase 1: local scan of 16 l's (x cached in regs)
#pragma unroll
    for (int l = 0; l < 16; ++l) {
        xv[l] = *(const uint4*)(base + (size_t)l * KD);
        const __hip_bfloat16* xs = (const __hip_bfloat16*)&xv[l];
#pragma unroll
        for (int k = 0; k < 8; ++k) {
            float v = __bfloat162float(xs[k]);
            float nr = lam[k].x * sr[k] - lam[k].y * si[k] + v;
            float ni = lam[k].x * si[k] + lam[k].y * sr[k];
            sr[k] = nr; si[k] = ni;
        }
    }
#pragma unroll
    for (int k = 0; k < 8; ++k) sl[sub][n0 + k] = make_float2(sr[k], si[k]);
    __syncthreads();

    // phase 2: per-n scan across the 8 sub-chunks (thread t owns n=t)
    {
        int n = t;
        float2 m16 = lamtab[n * 4 + 1];
        float2 c = sums[((size_t)b * KD + n) * 64 + seg];
        float cr = c.x, ci = c.y;
#pragma unroll
        for (int s2 = 0; s2 < 8; ++s2) {
            float2 loc = sl[s2][n];
            sl[s2][n] = make_float2(cr, ci);     // exclusive carry for sub-chunk
            float nr = m16.x * cr - m16.y * ci + loc.x;
            float ni = m16.x * ci + m16.y * cr + loc.y;
            cr = nr; ci = ni;
        }
    }
    __syncthreads();

    // phase 3 head: carries -> regs (sl is DEAD after this + barrier)
#pragma unroll
    for (int k = 0; k < 8; ++k) {
        float2 c = sl[sub][n0 + k];
        sr[k] = c.x; si[k] = c.y;
    }
    __syncthreads();   // all sl reads done; Ybuf writes may now alias

    // phase 3: rescan with carry, y (bf16x8) -> LDS fragment slots
    {
        const int kt_w = n0 >> 6, s_w = (n0 >> 5) & 1, lq_w = (n0 >> 3) & 3;
#pragma unroll
        for (int l = 0; l < 16; ++l) {
            const __hip_bfloat16* xs = (const __hip_bfloat16*)&xv[l];
            union { __hip_bfloat16 h[8]; uint4 u; } yv;
#pragma unroll
            for (int k = 0; k < 8; ++k) {
                float v = __bfloat162float(xs[k]);
                float nr = lam[k].x * sr[k] - lam[k].y * si[k] + v;
                float ni = lam[k].x * si[k] + lam[k].y * sr[k];
                sr[k] = nr; si[k] = ni;
                yv.h[k] = __float2bfloat16(nr);
            }
            int slotS = lq_w * 16 + (l ^ lq_w ^ (s_w << 2));   // XOR-swizzled
            *(uint4*)&Ybuf[kt_w][(sub * 2 + s_w) * 512 + slotS * 8] = yv.u;
        }
    }
    __syncthreads();

    // ============ GEMM2 MFMA: dtile looped, Ybuf read-only =============
    const int lane = t & 63, wave = t >> 6;
    const int wr = wave >> 1, wc = wave & 1;
    const int lm = lane & 15, lq = lane >> 4;
    const int col0 = seg * 128;
    float* Db = Dg + (size_t)b * KD * L_SEQ;

#pragma unroll
    for (int dtile = 0; dtile < 2; ++dtile) {
        const int row0 = dtile * 128;
        const __hip_bfloat16* Ab = Ag + (size_t)(row0 + wr * 64 + lm) * KD + lq * 8;

        f32x4 acc[4][4];
#pragma unroll
        for (int i = 0; i < 4; ++i)
#pragma unroll
            for (int j = 0; j < 4; ++j) acc[i][j] = {0.f, 0.f, 0.f, 0.f};

#pragma unroll
        for (int kt = 0; kt < 4; ++kt) {
#pragma unroll
            for (int s = 0; s < 2; ++s) {
                bf16x8 af[4], bfr[4];
#pragma unroll
                for (int i = 0; i < 4; ++i)
                    af[i] = *(const bf16x8*)(Ab + (size_t)(i * 16) * KD + kt * 64 + s * 32);
                int slotS = lq * 16 + (lm ^ lq ^ (s << 2));        // matching swizzle
#pragma unroll
                for (int j = 0; j < 4; ++j)
                    bfr[j] = *(const bf16x8*)&Ybuf[kt][((wc * 4 + j) * 2 + s) * 512 + slotS * 8];
#pragma unroll
                for (int i = 0; i < 4; ++i)
#pragma unroll
                    for (int j = 0; j < 4; ++j)
                        acc[i][j] = __builtin_amdgcn_mfma_f32_16x16x32_bf16(
                            af[i], bfr[j], acc[i][j], 0, 0, 0);
            }
        }

#pragma unroll
        for (int i = 0; i < 4; ++i) {
            int r0 = row0 + wr * 64 + i * 16 + lq * 4;
#pragma unroll
            for (int j = 0; j < 4; ++j) {
                int c = col0 + wc * 64 + j * 16 + lm;
#pragma unroll
                for (int r = 0; r < 4; ++r)
                    Db[(size_t)(r0 + r) * L_SEQ + c] = acc[i][j][r];
            }
        }
    }
}

// ---------------------------------------------------------------------------
// Launch
// ---------------------------------------------------------------------------
extern "C" void kernel_launch(void* const* d_in, const int* in_sizes, int n_in,
                              void* d_out, int out_size, void* d_ws, size_t ws_size,
                              hipStream_t stream) {
    const float* x      = (const float*)d_in[0];
    const float* A      = (const float*)d_in[1];
    const float* B      = (const float*)d_in[2];
    const float* log_dt = (const float*)d_in[3];
    const float* C      = (const float*)d_in[4];
    float* out = (float*)d_out;

    char* ws = (char*)d_ws;
    __hip_bfloat16* W1bf = (__hip_bfloat16*)(ws);                  // 128 KB
    __hip_bfloat16* Cbf  = (__hip_bfloat16*)(ws + (128 << 10));    // 128 KB
    float2*         lamtab = (float2*)(ws + (256 << 10));          // 8 KB
    float2*         sums = (float2*)(ws + (320 << 10));            // 1 MB
    __hip_bfloat16* xb_t = (__hip_bfloat16*)(ws + ((size_t)2 << 20)); // 32 MB

    prep<<<256, 256, 0, stream>>>(B, log_dt, C, A, W1bf, Cbf, lamtab);
    gemm1<<<dim3(2, 64, BATCH), 256, 0, stream>>>(x, W1bf, lamtab, xb_t, sums);
    scan_carry<<<BATCH * KD, 64, 0, stream>>>(lamtab, sums);
    scan_gemm2<<<dim3(64, BATCH), 256, 0, stream>>>(xb_t, lamtab, sums, Cbf, out);
}

// Round 9
// 179.169 us; speedup vs baseline: 1.0560x; 1.0038x over previous
//
#include <hip/hip_runtime.h>
#include <hip/hip_bf16.h>
#include <hip/hip_fp16.h>
#include <math.h>

#define BATCH 8
#define L_SEQ 8192
#define KD    256   // contraction dim for both GEMMs (c / n)

typedef __attribute__((ext_vector_type(8))) short bf16x8;
typedef __attribute__((ext_vector_type(4))) float f32x4;

__device__ __forceinline__ void async_ld16(const __hip_bfloat16* g, __hip_bfloat16* l) {
    __builtin_amdgcn_global_load_lds(
        (const __attribute__((address_space(1))) unsigned int*)g,
        (__attribute__((address_space(3))) unsigned int*)l, 16, 0, 0);
}

// ---------------------------------------------------------------------------
// prep: W1bf[n][c] = bf16(B[n][c]*dt[n]); Cbf[d][n] = bf16(C[d][n]);
// lamtab[n*4+0] = lambda, +1 = lambda^16, +2 = lambda^128, +3 = (dAr, dAi)
// ---------------------------------------------------------------------------
__global__ void prep(const float* __restrict__ B, const float* __restrict__ logdt,
                     const float* __restrict__ C, const float* __restrict__ A,
                     __hip_bfloat16* __restrict__ W1bf, __hip_bfloat16* __restrict__ Cbf,
                     float2* __restrict__ lamtab) {
    int i = blockIdx.x * 256 + threadIdx.x;
    W1bf[i] = __float2bfloat16(B[i] * expf(logdt[i >> 8]));
    Cbf[i]  = __float2bfloat16(C[i]);
    if (blockIdx.x == 0) {
        int n = threadIdx.x;
        float dt  = expf(logdt[n]);
        float dAr = -dt * log1pf(expf(A[2 * n]));
        float dAi = dt * A[2 * n + 1];
        float e1 = expf(dAr);
        lamtab[n * 4 + 0] = make_float2(e1 * cosf(dAi), e1 * sinf(dAi));
        float e16 = expf(16.f * dAr);
        lamtab[n * 4 + 1] = make_float2(e16 * cosf(16.f * dAi), e16 * sinf(16.f * dAi));
        float e128 = expf(128.f * dAr);
        lamtab[n * 4 + 2] = make_float2(e128 * cosf(128.f * dAi), e128 * sinf(128.f * dAi));
        lamtab[n * 4 + 3] = make_float2(dAr, dAi);
    }
}

// ---------------------------------------------------------------------------
// GEMM1 — identical to the verified r0 baseline EXCEPT the xb_t store is
// fp16 instead of bf16 (ONE intrinsic swap; sums epilogue untouched).
// Rationale: xb_t's bf16 quantization (7 mantissa bits) is the pipeline's
// dominant error source; fp16 (10 bits) cuts it 8x at zero traffic cost,
// buying numeric margin against the tolerance knife-edge.
// ---------------------------------------------------------------------------
__global__ __launch_bounds__(256) void gemm1(
        const float* __restrict__ X, const __hip_bfloat16* __restrict__ W1,
        const float2* __restrict__ lamtab,
        __half* __restrict__ XBT, float2* __restrict__ sums)
{
    __shared__ __hip_bfloat16 Abuf[16 * 512];
    __shared__ __hip_bfloat16 Bbuf[16 * 512];

    const int t = threadIdx.x, lane = t & 63, wave = t >> 6;
    const int wr = wave >> 1, wc = wave & 1;
    const int lm = lane & 15, lq = lane >> 4;
    const int seg = blockIdx.y;
    const int row0 = seg * 128;            // l
    const int col0 = blockIdx.x * 128;     // n
    const int b = blockIdx.z;
    const float* Xb = X + (size_t)b * KD * L_SEQ;

    // A-staging role: thread owns c-block of 8 (one LDS slot) x 4 l's
    const int c8  = t >> 5;        // 0..7
    const int l4  = (t & 31) * 4;  // 0..124
    const int s_w = c8 >> 2;       // k-half
    const int lq_w = c8 & 3;

    f32x4 acc[4][4];
#pragma unroll
    for (int i = 0; i < 4; ++i)
#pragma unroll
        for (int j = 0; j < 4; ++j) acc[i][j] = {0.f, 0.f, 0.f, 0.f};

    for (int k0 = 0; k0 < KD; k0 += 64) {
        // B tile (W1, k-contig) via async 16B direct-to-LDS
#pragma unroll
        for (int i = 0; i < 4; ++i) {
            int jb = wave * 4 + i, ct = jb >> 1, sB = jb & 1;
            const __hip_bfloat16* g =
                W1 + (size_t)(col0 + ct * 16 + lm) * KD + k0 + sB * 32 + lq * 8;
            async_ld16(g, &Bbuf[jb * 512 + lane * 8]);
        }
        // A tile: load x fp32 [c][l], transpose+cast into swizzled frag order
        float4 xv[8];
#pragma unroll
        for (int i = 0; i < 8; ++i)
            xv[i] = *(const float4*)(Xb + (size_t)(k0 + c8 * 8 + i) * L_SEQ + row0 + l4);
#pragma unroll
        for (int j = 0; j < 4; ++j) {
            int l = l4 + j;
            int rt = l >> 4, lmW = l & 15;
            union { __hip_bfloat16 h[8]; uint4 u; } pk;
#pragma unroll
            for (int i = 0; i < 8; ++i) {
                const float* f = (const float*)&xv[i];
                pk.h[i] = __float2bfloat16(f[j]);
            }
            int slot = (lmW ^ rt ^ (s_w << 3)) + 16 * lq_w;
            *(uint4*)&Abuf[(rt * 2 + s_w) * 512 + slot * 8] = pk.u;
        }
        __syncthreads();
#pragma unroll
        for (int s = 0; s < 2; ++s) {
            bf16x8 af[4], bfr[4];
#pragma unroll
            for (int i = 0; i < 4; ++i) {
                int rt = wr * 4 + i;
                int slot = (lm ^ rt ^ (s << 3)) + 16 * lq;
                af[i] = *(const bf16x8*)&Abuf[(rt * 2 + s) * 512 + slot * 8];
            }
#pragma unroll
            for (int j = 0; j < 4; ++j)
                bfr[j] = *(const bf16x8*)&Bbuf[((wc * 4 + j) * 2 + s) * 512 + lane * 8];
#pragma unroll
            for (int i = 0; i < 4; ++i)
#pragma unroll
                for (int j = 0; j < 4; ++j)
                    acc[i][j] = __builtin_amdgcn_mfma_f32_16x16x32_bf16(
                        af[i], bfr[j], acc[i][j], 0, 0, 0);
        }
        __syncthreads();
    }

    // ---- write xb_t (fp16 — THE one change)
    __half* Db = XBT + (size_t)b * L_SEQ * KD;
#pragma unroll
    for (int i = 0; i < 4; ++i) {
        int r0 = row0 + wr * 64 + i * 16 + lq * 4;
#pragma unroll
        for (int j = 0; j < 4; ++j) {
            int c = col0 + wc * 64 + j * 16 + lm;
#pragma unroll
            for (int r = 0; r < 4; ++r)
                Db[(size_t)(r0 + r) * KD + c] = __float2half(acc[i][j][r]);
        }
    }

    // ---- seg summaries: sum_l lambda^(127-l) * acc  (UNTOUCHED)
    float2 par[4];
#pragma unroll
    for (int j = 0; j < 4; ++j) {
        int n = col0 + wc * 64 + j * 16 + lm;
        float2 dA  = lamtab[n * 4 + 3];
        float2 lam = lamtab[n * 4 + 0];
        float m1r = lam.x, m1i = lam.y;      // lambda (FIXED: was lambda^-1)
        float sr = 0.f, si = 0.f;
#pragma unroll
        for (int i = 0; i < 4; ++i) {
            int lbase = wr * 64 + i * 16 + lq * 4;
            float p = (float)(127 - lbase - 3);
            float er = expf(dA.x * p);
            float wrr = er * cosf(dA.y * p), wii = er * sinf(dA.y * p);
            for (int r = 3; r >= 0; --r) {
                float v = acc[i][j][r];
                sr += wrr * v; si += wii * v;
                float nr = wrr * m1r - wii * m1i;
                float ni = wrr * m1i + wii * m1r;
                wrr = nr; wii = ni;
            }
        }
        sr += __shfl_xor(sr, 16); si += __shfl_xor(si, 16);
        sr += __shfl_xor(sr, 32); si += __shfl_xor(si, 32);
        par[j] = make_float2(sr, si);
    }
    float2* ssum = (float2*)Bbuf;   // reuse LDS (all waves past final sync)
    if (wr == 0 && lq == 0) {
#pragma unroll
        for (int j = 0; j < 4; ++j) ssum[wc * 64 + j * 16 + lm] = par[j];
    }
    __syncthreads();
    if (wr == 1 && lq == 0) {
#pragma unroll
        for (int j = 0; j < 4; ++j) {
            float2 o = ssum[wc * 64 + j * 16 + lm];
            int n = col0 + wc * 64 + j * 16 + lm;
            sums[((size_t)b * KD + n) * 64 + seg] =
                make_float2(par[j].x + o.x, par[j].y + o.y);
        }
    }
}

// ---------------------------------------------------------------------------
// scan_carry: per (b,n) wave-scan 64 inclusive seg summaries -> exclusive carries
// ---------------------------------------------------------------------------
__global__ __launch_bounds__(64) void scan_carry(
        const float2* __restrict__ lamtab, float2* __restrict__ sums) {
    const int lane = threadIdx.x;
    const int b = blockIdx.x >> 8, n = blockIdx.x & 255;
    float2 m = lamtab[n * 4 + 2];   // lambda^128
    float mr = m.x, mi = m.y;
    float2 s = sums[((size_t)b * KD + n) * 64 + lane];
    float vr = s.x, vi = s.y;
#pragma unroll
    for (int d = 1; d < 64; d <<= 1) {
        float ur = __shfl_up(vr, (unsigned)d);
        float ui = __shfl_up(vi, (unsigned)d);
        if (lane >= d) {
            float tr = mr * ur - mi * ui + vr;
            float ti = mr * ui + mi * ur + vi;
            vr = tr; vi = ti;
        }
        float m2r = mr * mr - mi * mi;
        float m2i = 2.0f * mr * mi;
        mr = m2r; mi = m2i;
    }
    float cr = __shfl_up(vr, 1u), ci = __shfl_up(vi, 1u);
    if (lane == 0) { cr = 0.f; ci = 0.f; }
    sums[((size_t)b * KD + n) * 64 + lane] = make_float2(cr, ci);
}

// ---------------------------------------------------------------------------
// FUSED scan+GEMM2 v2 (r8 structure, PASSED) — only change: xb_t decoded as
// fp16 instead of bf16 in phases 1/3. y is still bf16-quantized into Ybuf
// for the MFMA (unchanged), Cbf unchanged.
// ---------------------------------------------------------------------------
__global__ __launch_bounds__(256) void scan_gemm2(
        const __half* __restrict__ XBT,           // xb_t [B][L][256] (fp16, pre-scan)
        const float2* __restrict__ lamtab,
        const float2* __restrict__ sums,
        const __hip_bfloat16* __restrict__ Ag,    // Cbf [256][256]
        float* __restrict__ Dg)                   // out [B][256][L]
{
    __shared__ __align__(16) char lds_raw[65536];
    __hip_bfloat16 (*Ybuf)[16 * 512] = (__hip_bfloat16 (*)[16 * 512])lds_raw;
    float2 (*sl)[258] = (float2 (*)[258])lds_raw;   // aliases Ybuf head

    const int t = threadIdx.x;
    const int seg = blockIdx.x, b = blockIdx.y;
    const int sub = t >> 5, n0 = (t & 31) * 8;

    // ================= scan (r8 math; fp16 decode) =================
    const __half* base =
        XBT + ((size_t)b * L_SEQ + seg * 128 + sub * 16) * KD + n0;

    float2 lam[8];
#pragma unroll
    for (int k = 0; k < 8; ++k) lam[k] = lamtab[(n0 + k) * 4];

    uint4 xv[16];
    float sr[8], si[8];
#pragma unroll
    for (int k = 0; k < 8; ++k) { sr[k] = 0.f; si[k] = 0.f; }

    // phase 1: local scan of 16 l's (x cached in regs)
#pragma unroll
    for (int l = 0; l < 16; ++l) {
        xv[l] = *(const uint4*)(base + (size_t)l * KD);
        const __half* xs = (const __half*)&xv[l];
#pragma unroll
        for (int k = 0; k < 8; ++k) {
            float v = __half2float(xs[k]);
            float nr = lam[k].x * sr[k] - lam[k].y * si[k] + v;
            float ni = lam[k].x * si[k] + lam[k].y * sr[k];
            sr[k] = nr; si[k] = ni;
        }
    }
#pragma unroll
    for (int k = 0; k < 8; ++k) sl[sub][n0 + k] = make_float2(sr[k], si[k]);
    __syncthreads();

    // phase 2: per-n scan across the 8 sub-chunks (thread t owns n=t)
    {
        int n = t;
        float2 m16 = lamtab[n * 4 + 1];
        float2 c = sums[((size_t)b * KD + n) * 64 + seg];
        float cr = c.x, ci = c.y;
#pragma unroll
        for (int s2 = 0; s2 < 8; ++s2) {
            float2 loc = sl[s2][n];
            sl[s2][n] = make_float2(cr, ci);     // exclusive carry for sub-chunk
            float nr = m16.x * cr - m16.y * ci + loc.x;
            float ni = m16.x * ci + m16.y * cr + loc.y;
            cr = nr; ci = ni;
        }
    }
    __syncthreads();

    // phase 3 head: carries -> regs (sl is DEAD after this + barrier)
#pragma unroll
    for (int k = 0; k < 8; ++k) {
        float2 c = sl[sub][n0 + k];
        sr[k] = c.x; si[k] = c.y;
    }
    __syncthreads();   // all sl reads done; Ybuf writes may now alias

    // phase 3: rescan with carry, y (bf16x8) -> LDS fragment slots
    {
        const int kt_w = n0 >> 6, s_w = (n0 >> 5) & 1, lq_w = (n0 >> 3) & 3;
#pragma unroll
        for (int l = 0; l < 16; ++l) {
            const __half* xs = (const __half*)&xv[l];
            union { __hip_bfloat16 h[8]; uint4 u; } yv;
#pragma unroll
            for (int k = 0; k < 8; ++k) {
                float v = __half2float(xs[k]);
                float nr = lam[k].x * sr[k] - lam[k].y * si[k] + v;
                float ni = lam[k].x * si[k] + lam[k].y * sr[k];
                sr[k] = nr; si[k] = ni;
                yv.h[k] = __float2bfloat16(nr);
            }
            int slotS = lq_w * 16 + (l ^ lq_w ^ (s_w << 2));   // XOR-swizzled
            *(uint4*)&Ybuf[kt_w][(sub * 2 + s_w) * 512 + slotS * 8] = yv.u;
        }
    }
    __syncthreads();

    // ============ GEMM2 MFMA: dtile looped, Ybuf read-only =============
    const int lane = t & 63, wave = t >> 6;
    const int wr = wave >> 1, wc = wave & 1;
    const int lm = lane & 15, lq = lane >> 4;
    const int col0 = seg * 128;
    float* Db = Dg + (size_t)b * KD * L_SEQ;

#pragma unroll
    for (int dtile = 0; dtile < 2; ++dtile) {
        const int row0 = dtile * 128;
        const __hip_bfloat16* Ab = Ag + (size_t)(row0 + wr * 64 + lm) * KD + lq * 8;

        f32x4 acc[4][4];
#pragma unroll
        for (int i = 0; i < 4; ++i)
#pragma unroll
            for (int j = 0; j < 4; ++j) acc[i][j] = {0.f, 0.f, 0.f, 0.f};

#pragma unroll
        for (int kt = 0; kt < 4; ++kt) {
#pragma unroll
            for (int s = 0; s < 2; ++s) {
                bf16x8 af[4], bfr[4];
#pragma unroll
                for (int i = 0; i < 4; ++i)
                    af[i] = *(const bf16x8*)(Ab + (size_t)(i * 16) * KD + kt * 64 + s * 32);
                int slotS = lq * 16 + (lm ^ lq ^ (s << 2));        // matching swizzle
#pragma unroll
                for (int j = 0; j < 4; ++j)
                    bfr[j] = *(const bf16x8*)&Ybuf[kt][((wc * 4 + j) * 2 + s) * 512 + slotS * 8];
#pragma unroll
                for (int i = 0; i < 4; ++i)
#pragma unroll
                    for (int j = 0; j < 4; ++j)
                        acc[i][j] = __builtin_amdgcn_mfma_f32_16x16x32_bf16(
                            af[i], bfr[j], acc[i][j], 0, 0, 0);
            }
        }

#pragma unroll
        for (int i = 0; i < 4; ++i) {
            int r0 = row0 + wr * 64 + i * 16 + lq * 4;
#pragma unroll
            for (int j = 0; j < 4; ++j) {
                int c = col0 + wc * 64 + j * 16 + lm;
#pragma unroll
                for (int r = 0; r < 4; ++r)
                    Db[(size_t)(r0 + r) * L_SEQ + c] = acc[i][j][r];
            }
        }
    }
}

// ---------------------------------------------------------------------------
// Launch
// ---------------------------------------------------------------------------
extern "C" void kernel_launch(void* const* d_in, const int* in_sizes, int n_in,
                              void* d_out, int out_size, void* d_ws, size_t ws_size,
                              hipStream_t stream) {
    const float* x      = (const float*)d_in[0];
    const float* A      = (const float*)d_in[1];
    const float* B      = (const float*)d_in[2];
    const float* log_dt = (const float*)d_in[3];
    const float* C      = (const float*)d_in[4];
    float* out = (float*)d_out;

    char* ws = (char*)d_ws;
    __hip_bfloat16* W1bf = (__hip_bfloat16*)(ws);                  // 128 KB
    __hip_bfloat16* Cbf  = (__hip_bfloat16*)(ws + (128 << 10));    // 128 KB
    float2*         lamtab = (float2*)(ws + (256 << 10));          // 8 KB
    float2*         sums = (float2*)(ws + (320 << 10));            // 1 MB
    __half*         xb_t = (__half*)(ws + ((size_t)2 << 20));      // 32 MB (fp16)

    prep<<<256, 256, 0, stream>>>(B, log_dt, C, A, W1bf, Cbf, lamtab);
    gemm1<<<dim3(2, 64, BATCH), 256, 0, stream>>>(x, W1bf, lamtab, xb_t, sums);
    scan_carry<<<BATCH * KD, 64, 0, stream>>>(lamtab, sums);
    scan_gemm2<<<dim3(64, BATCH), 256, 0, stream>>>(xb_t, lamtab, sums, Cbf, out);
}